// Round 15
// baseline (532.710 us; speedup 1.0000x reference)
//
#include <hip/hip_runtime.h>
#include <math.h>
#include <stdint.h>

#define ROWS 8192   // B*S
#define DIM  1024
#define NH   8
#define DFF_ 4096
#define EPSF 1e-6f
#define SCALEQ 0.08838834764831845f  // DK^-0.5

typedef __attribute__((ext_vector_type(8))) short short8;
typedef __attribute__((ext_vector_type(4))) float f32x4;

// fast silu: native exp + rcp. x>>0 -> x; x<<0 -> 0.
__device__ __forceinline__ float siluf(float x) {
    float e = __expf(-x);
    return x * __builtin_amdgcn_rcpf(1.0f + e);
}
__device__ __forceinline__ unsigned short f2bf(float f) {
    uint32_t u = __float_as_uint(f);
    uint32_t r = (u + 0x7FFFu + ((u >> 16) & 1u)) >> 16;
    return (unsigned short)r;
}
__device__ __forceinline__ float bf2f(unsigned short u) {
    return __uint_as_float(((uint32_t)u) << 16);
}

// async global->LDS 16B (wave-uniform LDS base + lane*16)
__device__ __forceinline__ void async16(const void* g, void* l) {
    __builtin_amdgcn_global_load_lds(
        (const __attribute__((address_space(1))) uint32_t*)g,
        (__attribute__((address_space(3))) uint32_t*)l, 16, 0, 0);
}

// ---------------- RMSNorm -> bf16 out ----------------
__global__ void rmsnorm_bf16_kernel(const float* __restrict__ x, unsigned short* __restrict__ y) {
    int row = blockIdx.x;
    int tid = threadIdx.x;  // 256
    const float4* x4 = (const float4*)(x + (size_t)row * DIM);
    float4 v = x4[tid];
    float ss = v.x * v.x + v.y * v.y + v.z * v.z + v.w * v.w;
#pragma unroll
    for (int m = 1; m < 64; m <<= 1) ss += __shfl_xor(ss, m, 64);
    __shared__ float wss[4];
    if ((tid & 63) == 0) wss[tid >> 6] = ss;
    __syncthreads();
    float tot = wss[0] + wss[1] + wss[2] + wss[3];
    float r = rsqrtf(tot * (1.0f / 1024.0f) + EPSF);
    ushort4 o;
    o.x = f2bf(v.x * r); o.y = f2bf(v.y * r); o.z = f2bf(v.z * r); o.w = f2bf(v.w * r);
    ((ushort4*)(y + (size_t)row * DIM))[tid] = o;
}

// ---------------- fp32 -> bf16 transpose: W[K,N] -> WT[N,K] ----------------
__global__ void transpose_bf16_kernel(const float* __restrict__ W, unsigned short* __restrict__ WT,
                                      int K, int N) {
    __shared__ float tile[32][33];
    int n0 = blockIdx.x * 32, k0 = blockIdx.y * 32;
    int tx = threadIdx.x & 31, ty = threadIdx.x >> 5;
#pragma unroll
    for (int r = 0; r < 32; r += 8)
        tile[ty + r][tx] = W[(size_t)(k0 + ty + r) * N + n0 + tx];
    __syncthreads();
#pragma unroll
    for (int r = 0; r < 32; r += 8)
        WT[(size_t)(n0 + ty + r) * K + k0 + tx] = f2bf(tile[tx][ty + r]);
}

// five 1024x1024 transposes in one dispatch (z selects matrix)
__global__ void transpose5_kernel(const float* __restrict__ s0, const float* __restrict__ s1,
                                  const float* __restrict__ s2, const float* __restrict__ s3,
                                  const float* __restrict__ s4, unsigned short* __restrict__ dst) {
    __shared__ float tile[32][33];
    int z = blockIdx.z;
    const float* W = (z == 0) ? s0 : (z == 1) ? s1 : (z == 2) ? s2 : (z == 3) ? s3 : s4;
    unsigned short* WT = dst + (size_t)z * (1u << 20);
    int n0 = blockIdx.x * 32, k0 = blockIdx.y * 32;
    int tx = threadIdx.x & 31, ty = threadIdx.x >> 5;
#pragma unroll
    for (int r = 0; r < 32; r += 8)
        tile[ty + r][tx] = W[(size_t)(k0 + ty + r) * 1024 + n0 + tx];
    __syncthreads();
#pragma unroll
    for (int r = 0; r < 32; r += 8)
        WT[(size_t)(n0 + ty + r) * 1024 + k0 + tx] = f2bf(tile[tx][ty + r]);
}

// ================= 256x256 8-phase bf16 MFMA GEMM (T3+T4+T5, swizzled LDS) =================
#define G256_DECL \
    __shared__ __align__(16) unsigned short AL[2][2][256 * 32]; \
    __shared__ __align__(16) unsigned short BL[2][2][256 * 32]; \
    int tid = threadIdx.x; \
    int w = tid >> 6, lane = tid & 63; \
    int wm = w >> 2, wn = w & 3; \
    int lr = lane & 15; \
    int nwgx = gridDim.x; \
    int nwg = nwgx * gridDim.y; \
    int id = blockIdx.y * nwgx + blockIdx.x; \
    int cpx = nwg >> 3; \
    int nid = (id & 7) * cpx + (id >> 3); \
    int bxs = nid % nwgx, bys = nid / nwgx; \
    int bm = bys * 256, bn = bxs * 256; \
    int stg_r = w * 32 + (lane >> 2); \
    int stg_c = ((lane & 3) ^ ((lane >> 3) & 3)) * 8; \
    const unsigned short* Ag = A + (size_t)(bm + stg_r) * K + stg_c; \
    const unsigned short* Bg = BT + (size_t)(bn + stg_r) * K + stg_c; \
    int pc = ((lane >> 4) ^ ((lr >> 1) & 3)) * 8; \
    f32x4 acc[8][4] = {}; \
    short8 bf[4], af[4]; \
    int nt = K / 64;

#define G256_STAGE_A(buf, s, kto) do { \
    async16(Ag + (kto) + (s) * 32, &AL[buf][s][(w * 2 + 0) * 512]); \
    async16(Ag + (size_t)16 * K + (kto) + (s) * 32, &AL[buf][s][(w * 2 + 1) * 512]); \
} while (0)
#define G256_STAGE_B(buf, s, kto) do { \
    async16(Bg + (kto) + (s) * 32, &BL[buf][s][(w * 2 + 0) * 512]); \
    async16(Bg + (size_t)16 * K + (kto) + (s) * 32, &BL[buf][s][(w * 2 + 1) * 512]); \
} while (0)

#define G256_READ_B(cur, s) do { \
    _Pragma("unroll") \
    for (int j = 0; j < 4; ++j) \
        bf[j] = *(const short8*)&BL[cur][s][(wn * 64 + j * 16 + lr) * 32 + pc]; \
} while (0)
#define G256_READ_A(cur, s, rh) do { \
    _Pragma("unroll") \
    for (int i = 0; i < 4; ++i) \
        af[i] = *(const short8*)&AL[cur][s][(wm * 128 + (rh) * 64 + i * 16 + lr) * 32 + pc]; \
} while (0)

#define G256_MFMA(rh) do { \
    __builtin_amdgcn_s_barrier(); \
    asm volatile("s_waitcnt lgkmcnt(0)" ::: "memory"); \
    __builtin_amdgcn_s_setprio(1); \
    _Pragma("unroll") \
    for (int i = 0; i < 4; ++i) \
        _Pragma("unroll") \
        for (int j = 0; j < 4; ++j) \
            acc[(rh) * 4 + i][j] = __builtin_amdgcn_mfma_f32_16x16x32_bf16(af[i], bf[j], acc[(rh) * 4 + i][j], 0, 0, 0); \
    __builtin_amdgcn_s_setprio(0); \
} while (0)

#define G256_MAINLOOP \
    G256_STAGE_A(0, 0, 0); G256_STAGE_B(0, 0, 0); \
    G256_STAGE_A(0, 1, 0); G256_STAGE_B(0, 1, 0); \
    asm volatile("s_waitcnt vmcnt(0)" ::: "memory"); \
    __builtin_amdgcn_s_barrier(); \
    for (int t = 0; t < nt; ++t) { \
        int cur = t & 1, nxt = cur ^ 1; \
        bool pf = (t + 1 < nt); \
        int ktn = (t + 1) * 64; \
        G256_READ_B(cur, 0); \
        G256_READ_A(cur, 0, 0); \
        if (pf) G256_STAGE_A(nxt, 0, ktn); \
        G256_MFMA(0); \
        __builtin_amdgcn_s_barrier(); \
        G256_READ_A(cur, 0, 1); \
        if (pf) G256_STAGE_B(nxt, 0, ktn); \
        G256_MFMA(1); \
        asm volatile("s_waitcnt vmcnt(4)" ::: "memory"); \
        __builtin_amdgcn_s_barrier(); \
        G256_READ_B(cur, 1); \
        G256_READ_A(cur, 1, 0); \
        if (pf) G256_STAGE_A(nxt, 1, ktn); \
        G256_MFMA(0); \
        __builtin_amdgcn_s_barrier(); \
        G256_READ_A(cur, 1, 1); \
        if (pf) G256_STAGE_B(nxt, 1, ktn); \
        G256_MFMA(1); \
        asm volatile("s_waitcnt vmcnt(4)" ::: "memory"); \
        __builtin_amdgcn_s_barrier(); \
    }

// EPI: 0 none(f32), 2 res+acc(f32), 3 relu^2 -> bf16
template <int EPI, typename CT>
__global__ __launch_bounds__(512, 2) void gemm256(
    const unsigned short* __restrict__ A, const unsigned short* __restrict__ BT,
    CT* __restrict__ C, const float* __restrict__ res, int M, int N, int K) {
    G256_DECL
    G256_MAINLOOP

#pragma unroll
    for (int rf = 0; rf < 8; ++rf) {
        int gr0 = bm + wm * 128 + rf * 16 + (lane >> 4) * 4;
#pragma unroll
        for (int cf = 0; cf < 4; ++cf) {
            int gc = bn + wn * 64 + cf * 16 + lr;
#pragma unroll
            for (int r = 0; r < 4; ++r) {
                float v = acc[rf][cf][r];
                size_t idx = (size_t)(gr0 + r) * N + gc;
                if (EPI == 2) v += res[idx];
                else if (EPI == 3) { float t = fmaxf(v, 0.0f); v = t * t; }
                if constexpr (sizeof(CT) == 2) C[idx] = (CT)f2bf(v);
                else C[idx] = v;
            }
        }
    }
}

// fused QKVG 256^2
__global__ __launch_bounds__(512, 2) void qkvg256(
    const unsigned short* __restrict__ A, const unsigned short* __restrict__ BT,
    unsigned short* __restrict__ oq, unsigned short* __restrict__ ok,
    unsigned short* __restrict__ ov, unsigned short* __restrict__ og, int M, int K) {
    __shared__ float sums[256 * 4];
    G256_DECL
    G256_MAINLOOP

    int bsel = bn >> 10;
    int bnl = bn & 1023;
    if (bsel < 3) {
#pragma unroll
        for (int rf = 0; rf < 8; ++rf)
#pragma unroll
            for (int cf = 0; cf < 4; ++cf)
#pragma unroll
                for (int r = 0; r < 4; ++r)
                    acc[rf][cf][r] = siluf(acc[rf][cf][r]);
    }
    bool donorm = (bsel < 2);
    if (donorm) {
#pragma unroll
        for (int rf = 0; rf < 8; ++rf) {
#pragma unroll
            for (int r = 0; r < 4; ++r) {
                float p = acc[rf][0][r] * acc[rf][0][r] + acc[rf][1][r] * acc[rf][1][r] +
                          acc[rf][2][r] * acc[rf][2][r] + acc[rf][3][r] * acc[rf][3][r];
                p += __shfl_xor(p, 1, 16);
                p += __shfl_xor(p, 2, 16);
                p += __shfl_xor(p, 4, 16);
                p += __shfl_xor(p, 8, 16);
                if (lr == 0)
                    sums[(wm * 128 + rf * 16 + (lane >> 4) * 4 + r) * 4 + wn] = p;
            }
        }
        __syncthreads();
    }
    unsigned short* C = (bsel == 0) ? oq : (bsel == 1) ? ok : (bsel == 2) ? ov : og;
#pragma unroll
    for (int rf = 0; rf < 8; ++rf) {
#pragma unroll
        for (int r = 0; r < 4; ++r) {
            int lrow = wm * 128 + rf * 16 + (lane >> 4) * 4 + r;
            float rn = 1.0f;
            if (donorm)
                rn = rsqrtf(sums[lrow * 4 + (wn & 2)] + sums[lrow * 4 + (wn & 2) + 1] + EPSF);
            size_t gr = (size_t)(bm + lrow) * 1024;
#pragma unroll
            for (int cf = 0; cf < 4; ++cf) {
                int gc = bnl + wn * 64 + cf * 16 + lr;
                C[gr + gc] = f2bf(acc[rf][cf][r] * rn);
            }
        }
    }
}

// ================= 128x256 BK=32 GEMM, 3-buffer 2-tile-deep counted prefetch =================
// 72KB LDS -> 2 blocks/CU (16 waves/CU). Tile t issues loads for t+2; end-of-tile vmcnt(3)
// retires tile-(t+1)'s loads (invariant: 3 outstanding entering each tile). Tail: vmcnt(0).
template <int EPI>
__global__ __launch_bounds__(512) void gemm128n(
    const unsigned short* __restrict__ A, const unsigned short* __restrict__ BT,
    float* __restrict__ C, const float* __restrict__ res, int M, int N, int K) {
    __shared__ __align__(16) unsigned short AL[3 * 128 * 32];  // 24KB
    __shared__ __align__(16) unsigned short BL[3 * 256 * 32];  // 48KB
    int tid = threadIdx.x;
    int w = tid >> 6, lane = tid & 63;
    int wm = w >> 2, wn = w & 3;   // 2M x 4N waves; wave tile 64x64
    int lr = lane & 15;
    int nwgx = gridDim.x;
    int nwg = nwgx * gridDim.y;
    int id = blockIdx.y * nwgx + blockIdx.x;
    int cpx = nwg >> 3;
    int nid = (id & 7) * cpx + (id >> 3);
    int bxs = nid % nwgx, bys = nid / nwgx;
    int bm = bys * 128, bn = bxs * 256;

    // stage: A 512 chunks (row=tid>>2, phys chunk tid&3, src chunk ^(row>>1)&3);
    // B op l covers rows l*128+(tid>>2); (row>>1)&3 invariant under +128.
    int arow = tid >> 2;
    int ac = ((tid & 3) ^ ((tid >> 3) & 3)) * 8;
    const unsigned short* Aga = A + (size_t)(bm + arow) * K + ac;
    const unsigned short* Bga = BT + (size_t)(bn + arow) * K + ac;
    int pc = ((lane >> 4) ^ ((lr >> 1) & 3)) * 8;

    f32x4 acc[4][4] = {};
    short8 af[4], bf[4];
    int nt = K / 32;

#define G128_STAGE(bt, kto) do { \
    async16(Aga + (kto), &AL[(bt) * 4096 + tid * 8]); \
    async16(Bga + (kto), &BL[(bt) * 8192 + tid * 8]); \
    async16(Bga + (size_t)128 * K + (kto), &BL[(bt) * 8192 + (512 + tid) * 8]); \
} while (0)

    G128_STAGE(0, 0);
    G128_STAGE(1, 32);
    asm volatile("s_waitcnt vmcnt(3)" ::: "memory");  // tile-0 loads landed
    __builtin_amdgcn_s_barrier();
    int bt = 0, bs = 2;
    for (int t = 0; t < nt; ++t) {
        bool pf = (t + 2 < nt);
        if (pf) G128_STAGE(bs, (t + 2) * 32);
#pragma unroll
        for (int i = 0; i < 4; ++i)
            af[i] = *(const short8*)&AL[bt * 4096 + (wm * 64 + i * 16 + lr) * 32 + pc];
#pragma unroll
        for (int j = 0; j < 4; ++j)
            bf[j] = *(const short8*)&BL[bt * 8192 + (wn * 64 + j * 16 + lr) * 32 + pc];
        asm volatile("s_waitcnt lgkmcnt(0)" ::: "memory");
        __builtin_amdgcn_sched_barrier(0);
        __builtin_amdgcn_s_setprio(1);
#pragma unroll
        for (int i = 0; i < 4; ++i)
#pragma unroll
            for (int j = 0; j < 4; ++j)
                acc[i][j] = __builtin_amdgcn_mfma_f32_16x16x32_bf16(af[i], bf[j], acc[i][j], 0, 0, 0);
        __builtin_amdgcn_s_setprio(0);
        if (pf) asm volatile("s_waitcnt vmcnt(3)" ::: "memory");
        else    asm volatile("s_waitcnt vmcnt(0)" ::: "memory");
        __builtin_amdgcn_s_barrier();
        bt = (bt == 2) ? 0 : bt + 1;
        bs = (bs == 2) ? 0 : bs + 1;
    }
#undef G128_STAGE

#pragma unroll
    for (int i = 0; i < 4; ++i) {
        int gr0 = bm + wm * 64 + i * 16 + (lane >> 4) * 4;
#pragma unroll
        for (int j = 0; j < 4; ++j) {
            int gc = bn + wn * 64 + j * 16 + lr;
#pragma unroll
            for (int r = 0; r < 4; ++r) {
                float v = acc[i][j][r];
                size_t idx = (size_t)(gr0 + r) * N + gc;
                if (EPI == 2) v += res[idx];
                C[idx] = v;
            }
        }
    }
}

// ---------------- gated RMSNorm -> bf16 (gate is bf16) ----------------
__global__ void gating_kernel(const float* __restrict__ o, const unsigned short* __restrict__ gate,
                              const float* __restrict__ w, unsigned short* __restrict__ ob) {
    int row = blockIdx.x;
    int tid = threadIdx.x;
    const float4* op = (const float4*)(o + (size_t)row * DIM);
    float4 v = op[tid];
    float ss = v.x * v.x + v.y * v.y + v.z * v.z + v.w * v.w;
#pragma unroll
    for (int m = 1; m < 32; m <<= 1) ss += __shfl_xor(ss, m, 32);
    float r = rsqrtf(ss * (1.0f / 128.0f) + EPSF);
    ushort4 gu = ((const ushort4*)(gate + (size_t)row * DIM))[tid];
    float4 wv = ((const float4*)w)[tid & 31];
    ushort4 out;
    out.x = f2bf(v.x * r * wv.x * siluf(bf2f(gu.x)));
    out.y = f2bf(v.y * r * wv.y * siluf(bf2f(gu.y)));
    out.z = f2bf(v.z * r * wv.z * siluf(bf2f(gu.z)));
    out.w = f2bf(v.w * r * wv.w * siluf(bf2f(gu.w)));
    ((ushort4*)(ob + (size_t)row * DIM))[tid] = out;
}

// ---------------- small projections: beta, glog ----------------
__global__ void smallproj_kernel(const unsigned short* __restrict__ hbuf,
                                 const float* __restrict__ Wb, const float* __restrict__ Wa,
                                 const float* __restrict__ A_log, const float* __restrict__ dt_bias,
                                 float* __restrict__ Glog, float* __restrict__ Beta) {
    int row = blockIdx.x;
    int tid = threadIdx.x;  // 128
    __shared__ __align__(16) float hrow[1024];
    __shared__ float part[128];
    const ushort4* h4 = (const ushort4*)(hbuf + (size_t)row * DIM);
    ushort4 u0 = h4[tid * 2], u1 = h4[tid * 2 + 1];
    hrow[tid * 8 + 0] = bf2f(u0.x); hrow[tid * 8 + 1] = bf2f(u0.y);
    hrow[tid * 8 + 2] = bf2f(u0.z); hrow[tid * 8 + 3] = bf2f(u0.w);
    hrow[tid * 8 + 4] = bf2f(u1.x); hrow[tid * 8 + 5] = bf2f(u1.y);
    hrow[tid * 8 + 6] = bf2f(u1.z); hrow[tid * 8 + 7] = bf2f(u1.w);
    __syncthreads();
    int out = tid & 15, slice = tid >> 4;
    const float* W = (out < 8) ? Wb : Wa;
    int col = out & 7;
    int k0 = slice * 128;
    float p = 0.0f;
    for (int kk = 0; kk < 128; kk++) p += hrow[k0 + kk] * W[(size_t)(k0 + kk) * 8 + col];
    part[tid] = p;
    __syncthreads();
    if (tid < 16) {
        float sum = 0.0f;
#pragma unroll
        for (int sl = 0; sl < 8; sl++) sum += part[sl * 16 + tid];
        if (tid < 8) {
            Beta[(size_t)row * 8 + tid] = 1.0f / (1.0f + expf(-sum));
        } else {
            int hh = tid - 8;
            float xg = sum + dt_bias[hh];
            float sp = fmaxf(xg, 0.0f) + log1pf(expf(-fabsf(xg)));
            Glog[(size_t)row * 8 + hh] = -expf(A_log[hh]) * sp;
        }
    }
}

// ================= chunked gated delta rule =================
#define PRE_KB 0
#define PRE_QB 17408
#define PRE_YL 17408
#define PRE_LM 34816
#define PRE_MT 44032
#define PRE_FL 76800
#define PRE_SZ 77824

__global__ __launch_bounds__(256) void chunk_prep_kernel(
    const unsigned short* __restrict__ Q16, const unsigned short* __restrict__ K16,
    const unsigned short* __restrict__ V16, const float* __restrict__ Glog,
    const float* __restrict__ Beta,
    unsigned short* __restrict__ Wg, unsigned short* __restrict__ Ug,
    unsigned short* __restrict__ Qg, unsigned short* __restrict__ KTg,
    unsigned short* __restrict__ SMg, float* __restrict__ Pcs) {
    __shared__ __align__(16) unsigned char smem[PRE_SZ];
    unsigned short* Kb = (unsigned short*)(smem + PRE_KB);
    unsigned short* Qb = (unsigned short*)(smem + PRE_QB);
    unsigned short* Yl = (unsigned short*)(smem + PRE_YL);
    unsigned short* Lm = (unsigned short*)(smem + PRE_LM);
    float* betl = (float*)(smem + PRE_FL);
    float* Gl = betl + 64;
    float* Pl = Gl + 64;
    float* decf = Pl + 64;

    int blk = blockIdx.x;
    int bh = blk & 31, c = blk >> 5;
    int b = bh >> 3, h = bh & 7;
    int bhc = bh * 32 + c;
    int row0 = b * 2048 + c * 64;
    int col0 = h * 128;
    int tid = threadIdx.x;
    int wv = tid >> 6, lane = tid & 63;
    int lr = lane & 15, lk8 = (lane >> 4) * 8, l4 = (lane >> 4) * 4;

#pragma unroll
    for (int r = 0; r < 4; ++r) {
        int cc = tid + r * 256;
        int i = cc >> 4, jc = (cc & 15) * 8;
        *(short8*)&Kb[i * 136 + jc] = *(const short8*)(K16 + (size_t)(row0 + i) * DIM + col0 + jc);
        *(short8*)&Qb[i * 136 + jc] = *(const short8*)(Q16 + (size_t)(row0 + i) * DIM + col0 + jc);
    }
    {
        short8 z = {};
        for (int o = tid; o < 576; o += 256) ((short8*)Lm)[o] = z;
        for (int o = tid; o < 2048; o += 256) ((short8*)(smem + PRE_MT))[o] = z;
    }
    if (tid < 64) {
        float g = Glog[(size_t)(row0 + tid) * 8 + h];
        betl[tid] = Beta[(size_t)(row0 + tid) * 8 + h];
#pragma unroll
        for (int d = 1; d < 64; d <<= 1) {
            float t = __shfl_up(g, d, 64);
            if (tid >= d) g += t;
        }
        Gl[tid] = g;
        Pl[tid] = __expf(g);
        float g63 = __shfl(g, 63, 64);
        decf[tid] = __expf(g63 - g);
        if (tid == 63) Pcs[bhc] = __expf(g);
    }
    __syncthreads();

    for (int nt = 0; nt <= wv; nt++) {
        f32x4 acc = {};
#pragma unroll
        for (int kk = 0; kk < 4; kk++) {
            short8 af = *(const short8*)&Kb[(wv * 16 + lr) * 136 + kk * 32 + lk8];
            short8 bfr = *(const short8*)&Kb[(nt * 16 + lr) * 136 + kk * 32 + lk8];
            acc = __builtin_amdgcn_mfma_f32_16x16x32_bf16(af, bfr, acc, 0, 0, 0);
        }
#pragma unroll
        for (int r = 0; r < 4; r++) {
            int i = wv * 16 + l4 + r;
            int j = nt * 16 + lr;
            if (j < i) Lm[i * 72 + j] = f2bf(betl[i] * __expf(Gl[i] - Gl[j]) * acc[r]);
        }
    }
    for (int nt = 0; nt < 4; nt++) {
        f32x4 acc = {};
        if (nt <= wv) {
#pragma unroll
            for (int kk = 0; kk < 4; kk++) {
                short8 af = *(const short8*)&Qb[(wv * 16 + lr) * 136 + kk * 32 + lk8];
                short8 bfr = *(const short8*)&Kb[(nt * 16 + lr) * 136 + kk * 32 + lk8];
                acc = __builtin_amdgcn_mfma_f32_16x16x32_bf16(af, bfr, acc, 0, 0, 0);
            }
        }
#pragma unroll
        for (int r = 0; r < 4; r++) {
            int i = wv * 16 + l4 + r;
            int j = nt * 16 + lr;
            float vv = (nt <= wv && j <= i) ? SCALEQ * __expf(Gl[i] - Gl[j]) * acc[r] : 0.f;
            SMg[((size_t)bhc * 64 + i) * 64 + j] = f2bf(vv);
        }
    }
    {
        int d = tid & 127, ih = tid >> 7;
        for (int i0 = 0; i0 < 32; i0++) {
            int i = ih * 32 + i0;
            Qg[((size_t)bhc * 64 + i) * 128 + d] = f2bf(SCALEQ * Pl[i] * bf2f(Qb[i * 136 + d]));
        }
        for (int j8 = 0; j8 < 32; j8 += 8) {
            short8 v8;
#pragma unroll
            for (int e = 0; e < 8; e++) {
                int jj = ih * 32 + j8 + e;
                v8[e] = (short)f2bf(decf[jj] * bf2f(Kb[jj * 136 + d]));
            }
            *(short8*)&KTg[((size_t)bhc * 128 + d) * 64 + ih * 32 + j8] = v8;
        }
    }
    __syncthreads();

    int n = tid;
    bool isW = n < 128;
    int cW = n & 127;
    unsigned short* Gout = isW ? Wg : Ug;
    const unsigned short* Vcol = V16 + (size_t)row0 * DIM + col0 + cW;
    for (int bi = 0; bi < 4; ++bi) {
        if (bi > 0) {
            int ib = bi * 16;
#pragma unroll
            for (int t4 = 0; t4 < 4; ++t4) {
                int nt = wv * 4 + t4;
                f32x4 acc = {};
#pragma unroll
                for (int ks = 0; ks < 2; ++ks) {
                    short8 af = *(const short8*)&Lm[(ib + lr) * 72 + ks * 32 + lk8];
                    int nr = nt * 16 + lr;
                    int cj = ks * 4 + (lk8 >> 3);
                    short8 bfr = *(const short8*)(smem + PRE_MT + nr * 128 + (((cj ^ (nr & 7)) & 7) << 4));
                    acc = __builtin_amdgcn_mfma_f32_16x16x32_bf16(af, bfr, acc, 0, 0, 0);
                }
#pragma unroll
                for (int r = 0; r < 4; ++r)
                    Yl[(l4 + r) * 264 + nt * 16 + lr] = f2bf(acc[r]);
            }
        }
        __syncthreads();
        float xs[16];
#pragma unroll
        for (int ii = 0; ii < 16; ++ii) {
            int i = bi * 16 + ii;
            float a = isW ? betl[i] * Pl[i] * bf2f(Kb[i * 136 + cW])
                          : betl[i] * bf2f(Vcol[(size_t)i * DIM]);
            if (bi > 0) a -= bf2f(Yl[ii * 264 + n]);
#pragma unroll
            for (int j = 0; j < 15; ++j)
                if (j < ii) a = fmaf(-bf2f(Lm[i * 72 + bi * 16 + j]), xs[j], a);
            xs[ii] = a;
        }
        {
            short8 m0, m1;
#pragma unroll
            for (int e = 0; e < 8; ++e) { m0[e] = (short)f2bf(xs[e]); m1[e] = (short)f2bf(xs[8 + e]); }
            int cj0 = bi * 2, cj1 = bi * 2 + 1;
            *(short8*)(smem + PRE_MT + n * 128 + (((cj0 ^ (n & 7)) & 7) << 4)) = m0;
            *(short8*)(smem + PRE_MT + n * 128 + (((cj1 ^ (n & 7)) & 7) << 4)) = m1;
        }
#pragma unroll
        for (int ii = 0; ii < 16; ++ii)
            Gout[((size_t)bhc * 64 + bi * 16 + ii) * 128 + cW] = f2bf(xs[ii]);
        __syncthreads();
    }
}

// Phase 2 (MFMA): sequential over 32 chunks. Grid 256 = dvg*32 + bh, 256 thr (4 waves).
__global__ __launch_bounds__(256) void chunk_scan2_kernel(
    const unsigned short* __restrict__ Wg, const unsigned short* __restrict__ Ug,
    const unsigned short* __restrict__ Qg, const unsigned short* __restrict__ KTg,
    const unsigned short* __restrict__ SMg, const float* __restrict__ Pcs,
    float* __restrict__ O) {
    int blk = blockIdx.x;
    int bh = blk & 31, dvg = blk >> 5;
    int b = bh >> 3, h = bh & 7;
    int col16 = dvg * 16;
    int tid = threadIdx.x;
    int wv = tid >> 6, lane = tid & 63;
    int lr = lane & 15, lk8 = (lane >> 4) * 8, l4 = (lane >> 4) * 4;
    int i0 = wv * 16;

    __shared__ __align__(16) unsigned short Wl[64 * 136];
    __shared__ __align__(16) unsigned short Ql[64 * 136];
    __shared__ __align__(16) unsigned short KTl[128 * 72];
    __shared__ __align__(16) unsigned short SMl[64 * 72];
    __shared__ __align__(16) unsigned short Ul[64 * 24];
    __shared__ __align__(16) unsigned short STl[16 * 136];
    __shared__ __align__(16) unsigned short DTl[16 * 72];

    for (int e = tid; e < 16 * 136; e += 256) STl[e] = 0;

    f32x4 Sacc[2] = {};

    for (int c = 0; c < 32; c++) {
        int bhc = bh * 32 + c;
        size_t base8k = (size_t)bhc * 8192;
        float pc = Pcs[bhc];
#pragma unroll
        for (int r = 0; r < 4; r++) {
            int v = tid + r * 256;
            *(short8*)&Wl[(v >> 4) * 136 + (v & 15) * 8] = *(const short8*)(Wg + base8k + (size_t)v * 8);
            *(short8*)&Ql[(v >> 4) * 136 + (v & 15) * 8] = *(const short8*)(Qg + base8k + (size_t)v * 8);
            *(short8*)&KTl[(v >> 3) * 72 + (v & 7) * 8] = *(const short8*)(KTg + base8k + (size_t)v * 8);
        }
#pragma unroll
        for (int r = 0; r < 2; r++) {
            int v = tid + r * 256;
            *(short8*)&SMl[(v >> 3) * 72 + (v & 7) * 8] = *(const short8*)(SMg + (size_t)bhc * 4096 + (size_t)v * 8);
        }
        if (tid < 128) {
            int row = tid >> 1, hf = tid & 1;
            *(short8*)&Ul[row * 24 + hf * 8] =
                *(const short8*)(Ug + base8k + (size_t)row * 128 + col16 + hf * 8);
        }
        __syncthreads();

        f32x4 acc0 = {}, acc1 = {};
#pragma unroll
        for (int kd = 0; kd < 4; kd++) {
            short8 bfs = *(const short8*)&STl[lr * 136 + kd * 32 + lk8];
            short8 aw = *(const short8*)&Wl[(i0 + lr) * 136 + kd * 32 + lk8];
            short8 aq = *(const short8*)&Ql[(i0 + lr) * 136 + kd * 32 + lk8];
            acc0 = __builtin_amdgcn_mfma_f32_16x16x32_bf16(aw, bfs, acc0, 0, 0, 0);
            acc1 = __builtin_amdgcn_mfma_f32_16x16x32_bf16(aq, bfs, acc1, 0, 0, 0);
        }
        ushort4 dpk;
        dpk.x = f2bf(bf2f(Ul[(i0 + l4 + 0) * 24 + lr]) - acc0[0]);
        dpk.y = f2bf(bf2f(Ul[(i0 + l4 + 1) * 24 + lr]) - acc0[1]);
        dpk.z = f2bf(bf2f(Ul[(i0 + l4 + 2) * 24 + lr]) - acc0[2]);
        dpk.w = f2bf(bf2f(Ul[(i0 + l4 + 3) * 24 + lr]) - acc0[3]);
        *(ushort4*)&DTl[lr * 72 + i0 + l4] = dpk;
        __syncthreads();

#pragma unroll
        for (int dt = 0; dt < 2; dt++)
#pragma unroll
            for (int r = 0; r < 4; r++) Sacc[dt][r] *= pc;
#pragma unroll
        for (int kj = 0; kj < 2; kj++) {
            short8 bfd = *(const short8*)&DTl[lr * 72 + kj * 32 + lk8];
            short8 as = *(const short8*)&SMl[(i0 + lr) * 72 + kj * 32 + lk8];
            acc1 = __builtin_amdgcn_mfma_f32_16x16x32_bf16(as, bfd, acc1, 0, 0, 0);
#pragma unroll
            for (int dt = 0; dt < 2; dt++) {
                short8 ak = *(const short8*)&KTl[((2 * wv + dt) * 16 + lr) * 72 + kj * 32 + lk8];
                Sacc[dt] = __builtin_amdgcn_mfma_f32_16x16x32_bf16(ak, bfd, Sacc[dt], 0, 0, 0);
            }
        }
        {
            int orow0 = b * 2048 + c * 64 + i0 + l4;
            int ocol = h * 128 + col16 + lr;
#pragma unroll
            for (int r = 0; r < 4; r++)
                O[(size_t)(orow0 + r) * DIM + ocol] = acc1[r];
        }
#pragma unroll
        for (int dt = 0; dt < 2; dt++) {
            ushort4 sp;
            sp.x = f2bf(Sacc[dt][0]);
            sp.y = f2bf(Sacc[dt][1]);
            sp.z = f2bf(Sacc[dt][2]);
            sp.w = f2bf(Sacc[dt][3]);
            *(ushort4*)&STl[lr * 136 + (2 * wv + dt) * 16 + l4] = sp;
        }
        __syncthreads();
    }
}

extern "C" void kernel_launch(void* const* d_in, const int* in_sizes, int n_in,
                              void* d_out, int out_size, void* d_ws, size_t ws_size,
                              hipStream_t stream) {
    const float* x      = (const float*)d_in[0];
    const float* Wq     = (const float*)d_in[1];
    const float* Wk     = (const float*)d_in[2];
    const float* Wv     = (const float*)d_in[3];
    const float* Wb     = (const float*)d_in[4];
    const float* Wa     = (const float*)d_in[5];
    const float* A_log  = (const float*)d_in[6];
    const float* dt_b   = (const float*)d_in[7];
    const float* Wg_in  = (const float*)d_in[8];
    const float* o_norm = (const float*)d_in[9];
    const float* Wo     = (const float*)d_in[10];
    const float* W_fc   = (const float*)d_in[11];
    const float* W_proj = (const float*)d_in[12];
    float* out = (float*)d_out;

    const size_t MATE = (size_t)ROWS * DIM;  // 8M elems
    unsigned short* qb16 = (unsigned short*)d_ws;
    unsigned short* kb16 = qb16 + MATE;
    unsigned short* vb16 = kb16 + MATE;
    unsigned short* gt16 = vb16 + MATE;
    float* o_f = (float*)(gt16 + MATE);
    unsigned short* h_bf = (unsigned short*)(o_f + MATE);
    float* glog = (float*)(h_bf + MATE);
    float* beta = glog + (size_t)ROWS * NH;
    unsigned short* wts = (unsigned short*)(beta + (size_t)ROWS * NH);
    unsigned short* WqT = wts;                     // [4096,1024] concat Wq|Wk|Wv|Wg, then Wo
    unsigned short* WoT = wts + 4 * (1u << 20);
    unsigned short* WfcT = wts + 5 * (1u << 20);
    unsigned short* WprT = wts + 9 * (1u << 20);
    unsigned short* Wgb = wts + 13 * (1u << 20);
    unsigned short* Ugb = Wgb + (8u << 20);
    unsigned short* Qg2 = Ugb + (8u << 20);
    unsigned short* KTg = Qg2 + (8u << 20);
    unsigned short* SMg = KTg + (8u << 20);
    float* pcs = (float*)(SMg + (4u << 20));
    unsigned short* m_bf = h_bf;                   // alias (h dead after smallproj)
    unsigned short* o_bf = vb16;                   // alias (v dead after prep)
    unsigned short* fc_bf = qb16;                  // alias (q..gate dead by step 8)

    // 0. weight transposes -> bf16 [N,K]
    transpose5_kernel<<<dim3(32, 32, 5), 256, 0, stream>>>(Wq, Wk, Wv, Wg_in, Wo, WqT);
    transpose_bf16_kernel<<<dim3(128, 32), 256, 0, stream>>>(W_fc, WfcT, 1024, 4096);
    transpose_bf16_kernel<<<dim3(32, 128), 256, 0, stream>>>(W_proj, WprT, 4096, 1024);

    // 1. h = rms_norm(x) -> bf16
    rmsnorm_bf16_kernel<<<ROWS, 256, 0, stream>>>(x, h_bf);

    // 2. fused QKVG projection + silu + l2norm -> bf16 (256^2 8-phase)
    qkvg256<<<dim3(4096 / 256, ROWS / 256), 512, 0, stream>>>(
        h_bf, WqT, qb16, kb16, vb16, gt16, ROWS, DIM);

    // 3. beta/glog
    smallproj_kernel<<<ROWS, 128, 0, stream>>>(h_bf, Wb, Wa, A_log, dt_b, glog, beta);

    // 4. chunked delta rule
    chunk_prep_kernel<<<1024, 256, 0, stream>>>(qb16, kb16, vb16, glog, beta,
                                                Wgb, Ugb, Qg2, KTg, SMg, pcs);
    chunk_scan2_kernel<<<256, 256, 0, stream>>>(Wgb, Ugb, Qg2, KTg, SMg, pcs, o_f);

    // 5. gated RMSNorm -> o_bf
    gating_kernel<<<ROWS, 256, 0, stream>>>(o_f, gt16, o_norm, o_bf);

    // 6. d_out = x + o @ Wo (128x256 BK=32 3-buf, 256 blocks)
    gemm128n<2><<<dim3(1024 / 256, ROWS / 128), 512, 0, stream>>>(
        o_bf, WoT, out, x, ROWS, DIM, DIM);

    // 7. m = rms_norm(d_out) -> m_bf
    rmsnorm_bf16_kernel<<<ROWS, 256, 0, stream>>>(out, m_bf);

    // 8. fc = relu(m @ W_fc)^2 -> bf16 (256^2 8-phase)
    gemm256<3, unsigned short><<<dim3(DFF_ / 256, ROWS / 256), 512, 0, stream>>>(
        m_bf, WfcT, fc_bf, nullptr, ROWS, DFF_, DIM);

    // 9. d_out += fc @ W_proj (128x256 BK=32 3-buf, K=4096, 256 blocks)
    gemm128n<2><<<dim3(1024 / 256, ROWS / 128), 512, 0, stream>>>(
        fc_bf, WprT, out, out, ROWS, DIM, DFF_);
}

// Round 16
// 472.420 us; speedup vs baseline: 1.1276x; 1.1276x over previous
//
#include <hip/hip_runtime.h>
#include <math.h>
#include <stdint.h>

#define ROWS 8192   // B*S
#define DIM  1024
#define NH   8
#define DFF_ 4096
#define EPSF 1e-6f
#define SCALEQ 0.08838834764831845f  // DK^-0.5

typedef __attribute__((ext_vector_type(8))) short short8;
typedef __attribute__((ext_vector_type(4))) float f32x4;

// fast silu: native exp + rcp. x>>0 -> x; x<<0 -> 0.
__device__ __forceinline__ float siluf(float x) {
    float e = __expf(-x);
    return x * __builtin_amdgcn_rcpf(1.0f + e);
}
__device__ __forceinline__ unsigned short f2bf(float f) {
    uint32_t u = __float_as_uint(f);
    uint32_t r = (u + 0x7FFFu + ((u >> 16) & 1u)) >> 16;
    return (unsigned short)r;
}
__device__ __forceinline__ float bf2f(unsigned short u) {
    return __uint_as_float(((uint32_t)u) << 16);
}

// async global->LDS 16B (wave-uniform LDS base + lane*16)
__device__ __forceinline__ void async16(const void* g, void* l) {
    __builtin_amdgcn_global_load_lds(
        (const __attribute__((address_space(1))) uint32_t*)g,
        (__attribute__((address_space(3))) uint32_t*)l, 16, 0, 0);
}

// ---------------- RMSNorm -> bf16 out ----------------
__global__ void rmsnorm_bf16_kernel(const float* __restrict__ x, unsigned short* __restrict__ y) {
    int row = blockIdx.x;
    int tid = threadIdx.x;  // 256
    const float4* x4 = (const float4*)(x + (size_t)row * DIM);
    float4 v = x4[tid];
    float ss = v.x * v.x + v.y * v.y + v.z * v.z + v.w * v.w;
#pragma unroll
    for (int m = 1; m < 64; m <<= 1) ss += __shfl_xor(ss, m, 64);
    __shared__ float wss[4];
    if ((tid & 63) == 0) wss[tid >> 6] = ss;
    __syncthreads();
    float tot = wss[0] + wss[1] + wss[2] + wss[3];
    float r = rsqrtf(tot * (1.0f / 1024.0f) + EPSF);
    ushort4 o;
    o.x = f2bf(v.x * r); o.y = f2bf(v.y * r); o.z = f2bf(v.z * r); o.w = f2bf(v.w * r);
    ((ushort4*)(y + (size_t)row * DIM))[tid] = o;
}

// ---------------- fp32 -> bf16 transpose: W[K,N] -> WT[N,K] ----------------
__global__ void transpose_bf16_kernel(const float* __restrict__ W, unsigned short* __restrict__ WT,
                                      int K, int N) {
    __shared__ float tile[32][33];
    int n0 = blockIdx.x * 32, k0 = blockIdx.y * 32;
    int tx = threadIdx.x & 31, ty = threadIdx.x >> 5;
#pragma unroll
    for (int r = 0; r < 32; r += 8)
        tile[ty + r][tx] = W[(size_t)(k0 + ty + r) * N + n0 + tx];
    __syncthreads();
#pragma unroll
    for (int r = 0; r < 32; r += 8)
        WT[(size_t)(n0 + ty + r) * K + k0 + tx] = f2bf(tile[tx][ty + r]);
}

// five 1024x1024 transposes in one dispatch (z selects matrix)
__global__ void transpose5_kernel(const float* __restrict__ s0, const float* __restrict__ s1,
                                  const float* __restrict__ s2, const float* __restrict__ s3,
                                  const float* __restrict__ s4, unsigned short* __restrict__ dst) {
    __shared__ float tile[32][33];
    int z = blockIdx.z;
    const float* W = (z == 0) ? s0 : (z == 1) ? s1 : (z == 2) ? s2 : (z == 3) ? s3 : s4;
    unsigned short* WT = dst + (size_t)z * (1u << 20);
    int n0 = blockIdx.x * 32, k0 = blockIdx.y * 32;
    int tx = threadIdx.x & 31, ty = threadIdx.x >> 5;
#pragma unroll
    for (int r = 0; r < 32; r += 8)
        tile[ty + r][tx] = W[(size_t)(k0 + ty + r) * 1024 + n0 + tx];
    __syncthreads();
#pragma unroll
    for (int r = 0; r < 32; r += 8)
        WT[(size_t)(n0 + ty + r) * 1024 + k0 + tx] = f2bf(tile[tx][ty + r]);
}

// ================= 256x256 8-phase bf16 MFMA GEMM (T3+T4+T5, swizzled LDS) =================
#define G256_DECL \
    __shared__ __align__(16) unsigned short AL[2][2][256 * 32]; \
    __shared__ __align__(16) unsigned short BL[2][2][256 * 32]; \
    int tid = threadIdx.x; \
    int w = tid >> 6, lane = tid & 63; \
    int wm = w >> 2, wn = w & 3; \
    int lr = lane & 15; \
    int nwgx = gridDim.x; \
    int nwg = nwgx * gridDim.y; \
    int id = blockIdx.y * nwgx + blockIdx.x; \
    int cpx = nwg >> 3; \
    int nid = (id & 7) * cpx + (id >> 3); \
    int bxs = nid % nwgx, bys = nid / nwgx; \
    int bm = bys * 256, bn = bxs * 256; \
    int stg_r = w * 32 + (lane >> 2); \
    int stg_c = ((lane & 3) ^ ((lane >> 3) & 3)) * 8; \
    const unsigned short* Ag = A + (size_t)(bm + stg_r) * K + stg_c; \
    const unsigned short* Bg = BT + (size_t)(bn + stg_r) * K + stg_c; \
    int pc = ((lane >> 4) ^ ((lr >> 1) & 3)) * 8; \
    f32x4 acc[8][4] = {}; \
    short8 bf[4], af[4]; \
    int nt = K / 64;

#define G256_STAGE_A(buf, s, kto) do { \
    async16(Ag + (kto) + (s) * 32, &AL[buf][s][(w * 2 + 0) * 512]); \
    async16(Ag + (size_t)16 * K + (kto) + (s) * 32, &AL[buf][s][(w * 2 + 1) * 512]); \
} while (0)
#define G256_STAGE_B(buf, s, kto) do { \
    async16(Bg + (kto) + (s) * 32, &BL[buf][s][(w * 2 + 0) * 512]); \
    async16(Bg + (size_t)16 * K + (kto) + (s) * 32, &BL[buf][s][(w * 2 + 1) * 512]); \
} while (0)

#define G256_READ_B(cur, s) do { \
    _Pragma("unroll") \
    for (int j = 0; j < 4; ++j) \
        bf[j] = *(const short8*)&BL[cur][s][(wn * 64 + j * 16 + lr) * 32 + pc]; \
} while (0)
#define G256_READ_A(cur, s, rh) do { \
    _Pragma("unroll") \
    for (int i = 0; i < 4; ++i) \
        af[i] = *(const short8*)&AL[cur][s][(wm * 128 + (rh) * 64 + i * 16 + lr) * 32 + pc]; \
} while (0)

#define G256_MFMA(rh) do { \
    __builtin_amdgcn_s_barrier(); \
    asm volatile("s_waitcnt lgkmcnt(0)" ::: "memory"); \
    __builtin_amdgcn_s_setprio(1); \
    _Pragma("unroll") \
    for (int i = 0; i < 4; ++i) \
        _Pragma("unroll") \
        for (int j = 0; j < 4; ++j) \
            acc[(rh) * 4 + i][j] = __builtin_amdgcn_mfma_f32_16x16x32_bf16(af[i], bf[j], acc[(rh) * 4 + i][j], 0, 0, 0); \
    __builtin_amdgcn_s_setprio(0); \
} while (0)

#define G256_MAINLOOP \
    G256_STAGE_A(0, 0, 0); G256_STAGE_B(0, 0, 0); \
    G256_STAGE_A(0, 1, 0); G256_STAGE_B(0, 1, 0); \
    asm volatile("s_waitcnt vmcnt(0)" ::: "memory"); \
    __builtin_amdgcn_s_barrier(); \
    for (int t = 0; t < nt; ++t) { \
        int cur = t & 1, nxt = cur ^ 1; \
        bool pf = (t + 1 < nt); \
        int ktn = (t + 1) * 64; \
        G256_READ_B(cur, 0); \
        G256_READ_A(cur, 0, 0); \
        if (pf) G256_STAGE_A(nxt, 0, ktn); \
        G256_MFMA(0); \
        __builtin_amdgcn_s_barrier(); \
        G256_READ_A(cur, 0, 1); \
        if (pf) G256_STAGE_B(nxt, 0, ktn); \
        G256_MFMA(1); \
        asm volatile("s_waitcnt vmcnt(4)" ::: "memory"); \
        __builtin_amdgcn_s_barrier(); \
        G256_READ_B(cur, 1); \
        G256_READ_A(cur, 1, 0); \
        if (pf) G256_STAGE_A(nxt, 1, ktn); \
        G256_MFMA(0); \
        __builtin_amdgcn_s_barrier(); \
        G256_READ_A(cur, 1, 1); \
        if (pf) G256_STAGE_B(nxt, 1, ktn); \
        G256_MFMA(1); \
        asm volatile("s_waitcnt vmcnt(4)" ::: "memory"); \
        __builtin_amdgcn_s_barrier(); \
    }

// EPI: 0 none(f32), 2 res+acc(f32), 3 relu^2 -> bf16
template <int EPI, typename CT>
__global__ __launch_bounds__(512, 2) void gemm256(
    const unsigned short* __restrict__ A, const unsigned short* __restrict__ BT,
    CT* __restrict__ C, const float* __restrict__ res, int M, int N, int K) {
    G256_DECL
    G256_MAINLOOP

#pragma unroll
    for (int rf = 0; rf < 8; ++rf) {
        int gr0 = bm + wm * 128 + rf * 16 + (lane >> 4) * 4;
#pragma unroll
        for (int cf = 0; cf < 4; ++cf) {
            int gc = bn + wn * 64 + cf * 16 + lr;
#pragma unroll
            for (int r = 0; r < 4; ++r) {
                float v = acc[rf][cf][r];
                size_t idx = (size_t)(gr0 + r) * N + gc;
                if (EPI == 2) v += res[idx];
                else if (EPI == 3) { float t = fmaxf(v, 0.0f); v = t * t; }
                if constexpr (sizeof(CT) == 2) C[idx] = (CT)f2bf(v);
                else C[idx] = v;
            }
        }
    }
}

// fused QKVG 256^2
__global__ __launch_bounds__(512, 2) void qkvg256(
    const unsigned short* __restrict__ A, const unsigned short* __restrict__ BT,
    unsigned short* __restrict__ oq, unsigned short* __restrict__ ok,
    unsigned short* __restrict__ ov, unsigned short* __restrict__ og, int M, int K) {
    __shared__ float sums[256 * 4];
    G256_DECL
    G256_MAINLOOP

    int bsel = bn >> 10;
    int bnl = bn & 1023;
    if (bsel < 3) {
#pragma unroll
        for (int rf = 0; rf < 8; ++rf)
#pragma unroll
            for (int cf = 0; cf < 4; ++cf)
#pragma unroll
                for (int r = 0; r < 4; ++r)
                    acc[rf][cf][r] = siluf(acc[rf][cf][r]);
    }
    bool donorm = (bsel < 2);
    if (donorm) {
#pragma unroll
        for (int rf = 0; rf < 8; ++rf) {
#pragma unroll
            for (int r = 0; r < 4; ++r) {
                float p = acc[rf][0][r] * acc[rf][0][r] + acc[rf][1][r] * acc[rf][1][r] +
                          acc[rf][2][r] * acc[rf][2][r] + acc[rf][3][r] * acc[rf][3][r];
                p += __shfl_xor(p, 1, 16);
                p += __shfl_xor(p, 2, 16);
                p += __shfl_xor(p, 4, 16);
                p += __shfl_xor(p, 8, 16);
                if (lr == 0)
                    sums[(wm * 128 + rf * 16 + (lane >> 4) * 4 + r) * 4 + wn] = p;
            }
        }
        __syncthreads();
    }
    unsigned short* C = (bsel == 0) ? oq : (bsel == 1) ? ok : (bsel == 2) ? ov : og;
#pragma unroll
    for (int rf = 0; rf < 8; ++rf) {
#pragma unroll
        for (int r = 0; r < 4; ++r) {
            int lrow = wm * 128 + rf * 16 + (lane >> 4) * 4 + r;
            float rn = 1.0f;
            if (donorm)
                rn = rsqrtf(sums[lrow * 4 + (wn & 2)] + sums[lrow * 4 + (wn & 2) + 1] + EPSF);
            size_t gr = (size_t)(bm + lrow) * 1024;
#pragma unroll
            for (int cf = 0; cf < 4; ++cf) {
                int gc = bnl + wn * 64 + cf * 16 + lr;
                C[gr + gc] = f2bf(acc[rf][cf][r] * rn);
            }
        }
    }
}

// ================= 128x256 8-phase GEMM (R13 version: 2 sub-phases, counted vmcnt(3)) ======
template <int EPI>
__global__ __launch_bounds__(512, 2) void gemm128n(
    const unsigned short* __restrict__ A, const unsigned short* __restrict__ BT,
    float* __restrict__ C, const float* __restrict__ res, int M, int N, int K) {
    __shared__ __align__(16) unsigned short AL[2][2][128 * 32];
    __shared__ __align__(16) unsigned short BL[2][2][256 * 32];
    int tid = threadIdx.x;
    int w = tid >> 6, lane = tid & 63;
    int wm = w >> 2, wn = w & 3;
    int lr = lane & 15;
    int nwgx = gridDim.x;
    int nwg = nwgx * gridDim.y;
    int id = blockIdx.y * nwgx + blockIdx.x;
    int cpx = nwg >> 3;
    int nid = (id & 7) * cpx + (id >> 3);
    int bxs = nid % nwgx, bys = nid / nwgx;
    int bm = bys * 128, bn = bxs * 256;
    int stg_r = w * 16 + (lane >> 2);
    int stg_c = ((lane & 3) ^ ((lane >> 3) & 3)) * 8;
    const unsigned short* Ag = A + (size_t)(bm + stg_r) * K + stg_c;
    const unsigned short* Bg = BT + (size_t)(bn + stg_r) * K + stg_c;
    int pc = ((lane >> 4) ^ ((lr >> 1) & 3)) * 8;
    f32x4 acc[4][4] = {};
    short8 bf[4], af[4];
    int nt = K / 64;

#define G128_STAGE_A(buf, s, kto) \
    async16(Ag + (kto) + (s) * 32, &AL[buf][s][w * 512])
#define G128_STAGE_B(buf, s, kto) do { \
    async16(Bg + (kto) + (s) * 32, &BL[buf][s][w * 512]); \
    async16(Bg + (size_t)128 * K + (kto) + (s) * 32, &BL[buf][s][4096 + w * 512]); \
} while (0)
#define G128_READ(cur, s) do { \
    _Pragma("unroll") \
    for (int j = 0; j < 4; ++j) \
        bf[j] = *(const short8*)&BL[cur][s][(wn * 64 + j * 16 + lr) * 32 + pc]; \
    _Pragma("unroll") \
    for (int i = 0; i < 4; ++i) \
        af[i] = *(const short8*)&AL[cur][s][(wm * 64 + i * 16 + lr) * 32 + pc]; \
} while (0)
#define G128_MFMA() do { \
    __builtin_amdgcn_s_barrier(); \
    asm volatile("s_waitcnt lgkmcnt(0)" ::: "memory"); \
    __builtin_amdgcn_s_setprio(1); \
    _Pragma("unroll") \
    for (int i = 0; i < 4; ++i) \
        _Pragma("unroll") \
        for (int j = 0; j < 4; ++j) \
            acc[i][j] = __builtin_amdgcn_mfma_f32_16x16x32_bf16(af[i], bf[j], acc[i][j], 0, 0, 0); \
    __builtin_amdgcn_s_setprio(0); \
} while (0)

    G128_STAGE_A(0, 0, 0); G128_STAGE_B(0, 0, 0);
    G128_STAGE_A(0, 1, 0); G128_STAGE_B(0, 1, 0);
    asm volatile("s_waitcnt vmcnt(0)" ::: "memory");
    __builtin_amdgcn_s_barrier();
    for (int t = 0; t < nt; ++t) {
        int cur = t & 1, nxt = cur ^ 1;
        bool pf = (t + 1 < nt);
        int ktn = (t + 1) * 64;
        // phase 0: k-half 0
        G128_READ(cur, 0);
        if (pf) { G128_STAGE_A(nxt, 0, ktn); G128_STAGE_B(nxt, 0, ktn); }
        G128_MFMA();
        asm volatile("s_waitcnt vmcnt(3)" ::: "memory");
        __builtin_amdgcn_s_barrier();
        // phase 1: k-half 1
        G128_READ(cur, 1);
        if (pf) { G128_STAGE_A(nxt, 1, ktn); G128_STAGE_B(nxt, 1, ktn); }
        G128_MFMA();
        asm volatile("s_waitcnt vmcnt(3)" ::: "memory");
        __builtin_amdgcn_s_barrier();
    }

#pragma unroll
    for (int i = 0; i < 4; ++i) {
        int gr0 = bm + wm * 64 + i * 16 + (lane >> 4) * 4;
#pragma unroll
        for (int j = 0; j < 4; ++j) {
            int gc = bn + wn * 64 + j * 16 + lr;
#pragma unroll
            for (int r = 0; r < 4; ++r) {
                float v = acc[i][j][r];
                size_t idx = (size_t)(gr0 + r) * N + gc;
                if (EPI == 2) v += res[idx];
                C[idx] = v;
            }
        }
    }
#undef G128_STAGE_A
#undef G128_STAGE_B
#undef G128_READ
#undef G128_MFMA
}

// ---------------- gated RMSNorm -> bf16 (o and gate both bf16) ----------------
__global__ void gating_kernel(const unsigned short* __restrict__ o,
                              const unsigned short* __restrict__ gate,
                              const float* __restrict__ w, unsigned short* __restrict__ ob) {
    int row = blockIdx.x;
    int tid = threadIdx.x;
    ushort4 ou = ((const ushort4*)(o + (size_t)row * DIM))[tid];
    float vx = bf2f(ou.x), vy = bf2f(ou.y), vz = bf2f(ou.z), vw = bf2f(ou.w);
    float ss = vx * vx + vy * vy + vz * vz + vw * vw;
#pragma unroll
    for (int m = 1; m < 32; m <<= 1) ss += __shfl_xor(ss, m, 32);
    float r = rsqrtf(ss * (1.0f / 128.0f) + EPSF);
    ushort4 gu = ((const ushort4*)(gate + (size_t)row * DIM))[tid];
    float4 wv = ((const float4*)w)[tid & 31];
    ushort4 out;
    out.x = f2bf(vx * r * wv.x * siluf(bf2f(gu.x)));
    out.y = f2bf(vy * r * wv.y * siluf(bf2f(gu.y)));
    out.z = f2bf(vz * r * wv.z * siluf(bf2f(gu.z)));
    out.w = f2bf(vw * r * wv.w * siluf(bf2f(gu.w)));
    ((ushort4*)(ob + (size_t)row * DIM))[tid] = out;
}

// ---------------- small projections: beta, glog ----------------
__global__ void smallproj_kernel(const unsigned short* __restrict__ hbuf,
                                 const float* __restrict__ Wb, const float* __restrict__ Wa,
                                 const float* __restrict__ A_log, const float* __restrict__ dt_bias,
                                 float* __restrict__ Glog, float* __restrict__ Beta) {
    int row = blockIdx.x;
    int tid = threadIdx.x;  // 128
    __shared__ __align__(16) float hrow[1024];
    __shared__ float part[128];
    const ushort4* h4 = (const ushort4*)(hbuf + (size_t)row * DIM);
    ushort4 u0 = h4[tid * 2], u1 = h4[tid * 2 + 1];
    hrow[tid * 8 + 0] = bf2f(u0.x); hrow[tid * 8 + 1] = bf2f(u0.y);
    hrow[tid * 8 + 2] = bf2f(u0.z); hrow[tid * 8 + 3] = bf2f(u0.w);
    hrow[tid * 8 + 4] = bf2f(u1.x); hrow[tid * 8 + 5] = bf2f(u1.y);
    hrow[tid * 8 + 6] = bf2f(u1.z); hrow[tid * 8 + 7] = bf2f(u1.w);
    __syncthreads();
    int out = tid & 15, slice = tid >> 4;
    const float* W = (out < 8) ? Wb : Wa;
    int col = out & 7;
    int k0 = slice * 128;
    float p = 0.0f;
    for (int kk = 0; kk < 128; kk++) p += hrow[k0 + kk] * W[(size_t)(k0 + kk) * 8 + col];
    part[tid] = p;
    __syncthreads();
    if (tid < 16) {
        float sum = 0.0f;
#pragma unroll
        for (int sl = 0; sl < 8; sl++) sum += part[sl * 16 + tid];
        if (tid < 8) {
            Beta[(size_t)row * 8 + tid] = 1.0f / (1.0f + expf(-sum));
        } else {
            int hh = tid - 8;
            float xg = sum + dt_bias[hh];
            float sp = fmaxf(xg, 0.0f) + log1pf(expf(-fabsf(xg)));
            Glog[(size_t)row * 8 + hh] = -expf(A_log[hh]) * sp;
        }
    }
}

// ================= chunked gated delta rule =================
#define PRE_KB 0
#define PRE_QB 17408
#define PRE_YL 17408
#define PRE_LM 34816
#define PRE_MT 44032
#define PRE_FL 76800
#define PRE_SZ 77824

__global__ __launch_bounds__(256) void chunk_prep_kernel(
    const unsigned short* __restrict__ Q16, const unsigned short* __restrict__ K16,
    const unsigned short* __restrict__ V16, const float* __restrict__ Glog,
    const float* __restrict__ Beta,
    unsigned short* __restrict__ Wg, unsigned short* __restrict__ Ug,
    unsigned short* __restrict__ Qg, unsigned short* __restrict__ KTg,
    unsigned short* __restrict__ SMg, float* __restrict__ Pcs) {
    __shared__ __align__(16) unsigned char smem[PRE_SZ];
    unsigned short* Kb = (unsigned short*)(smem + PRE_KB);
    unsigned short* Qb = (unsigned short*)(smem + PRE_QB);
    unsigned short* Yl = (unsigned short*)(smem + PRE_YL);
    unsigned short* Lm = (unsigned short*)(smem + PRE_LM);
    float* betl = (float*)(smem + PRE_FL);
    float* Gl = betl + 64;
    float* Pl = Gl + 64;
    float* decf = Pl + 64;

    int blk = blockIdx.x;
    int bh = blk & 31, c = blk >> 5;
    int b = bh >> 3, h = bh & 7;
    int bhc = bh * 32 + c;
    int row0 = b * 2048 + c * 64;
    int col0 = h * 128;
    int tid = threadIdx.x;
    int wv = tid >> 6, lane = tid & 63;
    int lr = lane & 15, lk8 = (lane >> 4) * 8, l4 = (lane >> 4) * 4;

#pragma unroll
    for (int r = 0; r < 4; ++r) {
        int cc = tid + r * 256;
        int i = cc >> 4, jc = (cc & 15) * 8;
        *(short8*)&Kb[i * 136 + jc] = *(const short8*)(K16 + (size_t)(row0 + i) * DIM + col0 + jc);
        *(short8*)&Qb[i * 136 + jc] = *(const short8*)(Q16 + (size_t)(row0 + i) * DIM + col0 + jc);
    }
    {
        short8 z = {};
        for (int o = tid; o < 576; o += 256) ((short8*)Lm)[o] = z;
        for (int o = tid; o < 2048; o += 256) ((short8*)(smem + PRE_MT))[o] = z;
    }
    if (tid < 64) {
        float g = Glog[(size_t)(row0 + tid) * 8 + h];
        betl[tid] = Beta[(size_t)(row0 + tid) * 8 + h];
#pragma unroll
        for (int d = 1; d < 64; d <<= 1) {
            float t = __shfl_up(g, d, 64);
            if (tid >= d) g += t;
        }
        Gl[tid] = g;
        Pl[tid] = __expf(g);
        float g63 = __shfl(g, 63, 64);
        decf[tid] = __expf(g63 - g);
        if (tid == 63) Pcs[bhc] = __expf(g);
    }
    __syncthreads();

    for (int nt = 0; nt <= wv; nt++) {
        f32x4 acc = {};
#pragma unroll
        for (int kk = 0; kk < 4; kk++) {
            short8 af = *(const short8*)&Kb[(wv * 16 + lr) * 136 + kk * 32 + lk8];
            short8 bfr = *(const short8*)&Kb[(nt * 16 + lr) * 136 + kk * 32 + lk8];
            acc = __builtin_amdgcn_mfma_f32_16x16x32_bf16(af, bfr, acc, 0, 0, 0);
        }
#pragma unroll
        for (int r = 0; r < 4; r++) {
            int i = wv * 16 + l4 + r;
            int j = nt * 16 + lr;
            if (j < i) Lm[i * 72 + j] = f2bf(betl[i] * __expf(Gl[i] - Gl[j]) * acc[r]);
        }
    }
    for (int nt = 0; nt < 4; nt++) {
        f32x4 acc = {};
        if (nt <= wv) {
#pragma unroll
            for (int kk = 0; kk < 4; kk++) {
                short8 af = *(const short8*)&Qb[(wv * 16 + lr) * 136 + kk * 32 + lk8];
                short8 bfr = *(const short8*)&Kb[(nt * 16 + lr) * 136 + kk * 32 + lk8];
                acc = __builtin_amdgcn_mfma_f32_16x16x32_bf16(af, bfr, acc, 0, 0, 0);
            }
        }
#pragma unroll
        for (int r = 0; r < 4; r++) {
            int i = wv * 16 + l4 + r;
            int j = nt * 16 + lr;
            float vv = (nt <= wv && j <= i) ? SCALEQ * __expf(Gl[i] - Gl[j]) * acc[r] : 0.f;
            SMg[((size_t)bhc * 64 + i) * 64 + j] = f2bf(vv);
        }
    }
    {
        int d = tid & 127, ih = tid >> 7;
        for (int i0 = 0; i0 < 32; i0++) {
            int i = ih * 32 + i0;
            Qg[((size_t)bhc * 64 + i) * 128 + d] = f2bf(SCALEQ * Pl[i] * bf2f(Qb[i * 136 + d]));
        }
        for (int j8 = 0; j8 < 32; j8 += 8) {
            short8 v8;
#pragma unroll
            for (int e = 0; e < 8; e++) {
                int jj = ih * 32 + j8 + e;
                v8[e] = (short)f2bf(decf[jj] * bf2f(Kb[jj * 136 + d]));
            }
            *(short8*)&KTg[((size_t)bhc * 128 + d) * 64 + ih * 32 + j8] = v8;
        }
    }
    __syncthreads();

    int n = tid;
    bool isW = n < 128;
    int cW = n & 127;
    unsigned short* Gout = isW ? Wg : Ug;
    const unsigned short* Vcol = V16 + (size_t)row0 * DIM + col0 + cW;
    for (int bi = 0; bi < 4; ++bi) {
        if (bi > 0) {
            int ib = bi * 16;
#pragma unroll
            for (int t4 = 0; t4 < 4; ++t4) {
                int nt = wv * 4 + t4;
                f32x4 acc = {};
#pragma unroll
                for (int ks = 0; ks < 2; ++ks) {
                    short8 af = *(const short8*)&Lm[(ib + lr) * 72 + ks * 32 + lk8];
                    int nr = nt * 16 + lr;
                    int cj = ks * 4 + (lk8 >> 3);
                    short8 bfr = *(const short8*)(smem + PRE_MT + nr * 128 + (((cj ^ (nr & 7)) & 7) << 4));
                    acc = __builtin_amdgcn_mfma_f32_16x16x32_bf16(af, bfr, acc, 0, 0, 0);
                }
#pragma unroll
                for (int r = 0; r < 4; ++r)
                    Yl[(l4 + r) * 264 + nt * 16 + lr] = f2bf(acc[r]);
            }
        }
        __syncthreads();
        float xs[16];
#pragma unroll
        for (int ii = 0; ii < 16; ++ii) {
            int i = bi * 16 + ii;
            float a = isW ? betl[i] * Pl[i] * bf2f(Kb[i * 136 + cW])
                          : betl[i] * bf2f(Vcol[(size_t)i * DIM]);
            if (bi > 0) a -= bf2f(Yl[ii * 264 + n]);
#pragma unroll
            for (int j = 0; j < 15; ++j)
                if (j < ii) a = fmaf(-bf2f(Lm[i * 72 + bi * 16 + j]), xs[j], a);
            xs[ii] = a;
        }
        {
            short8 m0, m1;
#pragma unroll
            for (int e = 0; e < 8; ++e) { m0[e] = (short)f2bf(xs[e]); m1[e] = (short)f2bf(xs[8 + e]); }
            int cj0 = bi * 2, cj1 = bi * 2 + 1;
            *(short8*)(smem + PRE_MT + n * 128 + (((cj0 ^ (n & 7)) & 7) << 4)) = m0;
            *(short8*)(smem + PRE_MT + n * 128 + (((cj1 ^ (n & 7)) & 7) << 4)) = m1;
        }
#pragma unroll
        for (int ii = 0; ii < 16; ++ii)
            Gout[((size_t)bhc * 64 + bi * 16 + ii) * 128 + cW] = f2bf(xs[ii]);
        __syncthreads();
    }
}

// Phase 2 (MFMA): sequential over 32 chunks. Grid 256 = dvg*32 + bh, 256 thr (4 waves).
// O output is bf16 (rms-normalized next, so rounding is benign).
__global__ __launch_bounds__(256) void chunk_scan2_kernel(
    const unsigned short* __restrict__ Wg, const unsigned short* __restrict__ Ug,
    const unsigned short* __restrict__ Qg, const unsigned short* __restrict__ KTg,
    const unsigned short* __restrict__ SMg, const float* __restrict__ Pcs,
    unsigned short* __restrict__ O) {
    int blk = blockIdx.x;
    int bh = blk & 31, dvg = blk >> 5;
    int b = bh >> 3, h = bh & 7;
    int col16 = dvg * 16;
    int tid = threadIdx.x;
    int wv = tid >> 6, lane = tid & 63;
    int lr = lane & 15, lk8 = (lane >> 4) * 8, l4 = (lane >> 4) * 4;
    int i0 = wv * 16;

    __shared__ __align__(16) unsigned short Wl[64 * 136];
    __shared__ __align__(16) unsigned short Ql[64 * 136];
    __shared__ __align__(16) unsigned short KTl[128 * 72];
    __shared__ __align__(16) unsigned short SMl[64 * 72];
    __shared__ __align__(16) unsigned short Ul[64 * 24];
    __shared__ __align__(16) unsigned short STl[16 * 136];
    __shared__ __align__(16) unsigned short DTl[16 * 72];

    for (int e = tid; e < 16 * 136; e += 256) STl[e] = 0;

    f32x4 Sacc[2] = {};

    for (int c = 0; c < 32; c++) {
        int bhc = bh * 32 + c;
        size_t base8k = (size_t)bhc * 8192;
        float pc = Pcs[bhc];
#pragma unroll
        for (int r = 0; r < 4; r++) {
            int v = tid + r * 256;
            *(short8*)&Wl[(v >> 4) * 136 + (v & 15) * 8] = *(const short8*)(Wg + base8k + (size_t)v * 8);
            *(short8*)&Ql[(v >> 4) * 136 + (v & 15) * 8] = *(const short8*)(Qg + base8k + (size_t)v * 8);
            *(short8*)&KTl[(v >> 3) * 72 + (v & 7) * 8] = *(const short8*)(KTg + base8k + (size_t)v * 8);
        }
#pragma unroll
        for (int r = 0; r < 2; r++) {
            int v = tid + r * 256;
            *(short8*)&SMl[(v >> 3) * 72 + (v & 7) * 8] = *(const short8*)(SMg + (size_t)bhc * 4096 + (size_t)v * 8);
        }
        if (tid < 128) {
            int row = tid >> 1, hf = tid & 1;
            *(short8*)&Ul[row * 24 + hf * 8] =
                *(const short8*)(Ug + base8k + (size_t)row * 128 + col16 + hf * 8);
        }
        __syncthreads();

        f32x4 acc0 = {}, acc1 = {};
#pragma unroll
        for (int kd = 0; kd < 4; kd++) {
            short8 bfs = *(const short8*)&STl[lr * 136 + kd * 32 + lk8];
            short8 aw = *(const short8*)&Wl[(i0 + lr) * 136 + kd * 32 + lk8];
            short8 aq = *(const short8*)&Ql[(i0 + lr) * 136 + kd * 32 + lk8];
            acc0 = __builtin_amdgcn_mfma_f32_16x16x32_bf16(aw, bfs, acc0, 0, 0, 0);
            acc1 = __builtin_amdgcn_mfma_f32_16x16x32_bf16(aq, bfs, acc1, 0, 0, 0);
        }
        ushort4 dpk;
        dpk.x = f2bf(bf2f(Ul[(i0 + l4 + 0) * 24 + lr]) - acc0[0]);
        dpk.y = f2bf(bf2f(Ul[(i0 + l4 + 1) * 24 + lr]) - acc0[1]);
        dpk.z = f2bf(bf2f(Ul[(i0 + l4 + 2) * 24 + lr]) - acc0[2]);
        dpk.w = f2bf(bf2f(Ul[(i0 + l4 + 3) * 24 + lr]) - acc0[3]);
        *(ushort4*)&DTl[lr * 72 + i0 + l4] = dpk;
        __syncthreads();

#pragma unroll
        for (int dt = 0; dt < 2; dt++)
#pragma unroll
            for (int r = 0; r < 4; r++) Sacc[dt][r] *= pc;
#pragma unroll
        for (int kj = 0; kj < 2; kj++) {
            short8 bfd = *(const short8*)&DTl[lr * 72 + kj * 32 + lk8];
            short8 as = *(const short8*)&SMl[(i0 + lr) * 72 + kj * 32 + lk8];
            acc1 = __builtin_amdgcn_mfma_f32_16x16x32_bf16(as, bfd, acc1, 0, 0, 0);
#pragma unroll
            for (int dt = 0; dt < 2; dt++) {
                short8 ak = *(const short8*)&KTl[((2 * wv + dt) * 16 + lr) * 72 + kj * 32 + lk8];
                Sacc[dt] = __builtin_amdgcn_mfma_f32_16x16x32_bf16(ak, bfd, Sacc[dt], 0, 0, 0);
            }
        }
        {
            int orow0 = b * 2048 + c * 64 + i0 + l4;
            int ocol = h * 128 + col16 + lr;
#pragma unroll
            for (int r = 0; r < 4; r++)
                O[(size_t)(orow0 + r) * DIM + ocol] = f2bf(acc1[r]);
        }
#pragma unroll
        for (int dt = 0; dt < 2; dt++) {
            ushort4 sp;
            sp.x = f2bf(Sacc[dt][0]);
            sp.y = f2bf(Sacc[dt][1]);
            sp.z = f2bf(Sacc[dt][2]);
            sp.w = f2bf(Sacc[dt][3]);
            *(ushort4*)&STl[lr * 136 + (2 * wv + dt) * 16 + l4] = sp;
        }
        __syncthreads();
    }
}

extern "C" void kernel_launch(void* const* d_in, const int* in_sizes, int n_in,
                              void* d_out, int out_size, void* d_ws, size_t ws_size,
                              hipStream_t stream) {
    const float* x      = (const float*)d_in[0];
    const float* Wq     = (const float*)d_in[1];
    const float* Wk     = (const float*)d_in[2];
    const float* Wv     = (const float*)d_in[3];
    const float* Wb     = (const float*)d_in[4];
    const float* Wa     = (const float*)d_in[5];
    const float* A_log  = (const float*)d_in[6];
    const float* dt_b   = (const float*)d_in[7];
    const float* Wg_in  = (const float*)d_in[8];
    const float* o_norm = (const float*)d_in[9];
    const float* Wo     = (const float*)d_in[10];
    const float* W_fc   = (const float*)d_in[11];
    const float* W_proj = (const float*)d_in[12];
    float* out = (float*)d_out;

    const size_t MATE = (size_t)ROWS * DIM;  // 8M elems
    unsigned short* qb16 = (unsigned short*)d_ws;
    unsigned short* kb16 = qb16 + MATE;
    unsigned short* vb16 = kb16 + MATE;
    unsigned short* gt16 = vb16 + MATE;
    unsigned short* o16 = gt16 + MATE;             // bf16 o (scan2 output)
    unsigned short* h_bf = o16 + MATE;
    float* glog = (float*)(h_bf + MATE);
    float* beta = glog + (size_t)ROWS * NH;
    unsigned short* wts = (unsigned short*)(beta + (size_t)ROWS * NH);
    unsigned short* WqT = wts;                     // [4096,1024] concat Wq|Wk|Wv|Wg, then Wo
    unsigned short* WoT = wts + 4 * (1u << 20);
    unsigned short* WfcT = wts + 5 * (1u << 20);
    unsigned short* WprT = wts + 9 * (1u << 20);
    unsigned short* Wgb = wts + 13 * (1u << 20);
    unsigned short* Ugb = Wgb + (8u << 20);
    unsigned short* Qg2 = Ugb + (8u << 20);
    unsigned short* KTg = Qg2 + (8u << 20);
    unsigned short* SMg = KTg + (8u << 20);
    float* pcs = (float*)(SMg + (4u << 20));
    unsigned short* m_bf = h_bf;                   // alias (h dead after smallproj)
    unsigned short* o_bf = vb16;                   // alias (v dead after prep)
    unsigned short* fc_bf = qb16;                  // alias (q..gate dead by step 8)

    // 0. weight transposes -> bf16 [N,K]
    transpose5_kernel<<<dim3(32, 32, 5), 256, 0, stream>>>(Wq, Wk, Wv, Wg_in, Wo, WqT);
    transpose_bf16_kernel<<<dim3(128, 32), 256, 0, stream>>>(W_fc, WfcT, 1024, 4096);
    transpose_bf16_kernel<<<dim3(32, 128), 256, 0, stream>>>(W_proj, WprT, 4096, 1024);

    // 1. h = rms_norm(x) -> bf16
    rmsnorm_bf16_kernel<<<ROWS, 256, 0, stream>>>(x, h_bf);

    // 2. fused QKVG projection + silu + l2norm -> bf16 (256^2 8-phase)
    qkvg256<<<dim3(4096 / 256, ROWS / 256), 512, 0, stream>>>(
        h_bf, WqT, qb16, kb16, vb16, gt16, ROWS, DIM);

    // 3. beta/glog
    smallproj_kernel<<<ROWS, 128, 0, stream>>>(h_bf, Wb, Wa, A_log, dt_b, glog, beta);

    // 4. chunked delta rule
    chunk_prep_kernel<<<1024, 256, 0, stream>>>(qb16, kb16, vb16, glog, beta,
                                                Wgb, Ugb, Qg2, KTg, SMg, pcs);
    chunk_scan2_kernel<<<256, 256, 0, stream>>>(Wgb, Ugb, Qg2, KTg, SMg, pcs, o16);

    // 5. gated RMSNorm -> o_bf
    gating_kernel<<<ROWS, 256, 0, stream>>>(o16, gt16, o_norm, o_bf);

    // 6. d_out = x + o @ Wo (128x256 8-phase, 256 blocks)
    gemm128n<2><<<dim3(1024 / 256, ROWS / 128), 512, 0, stream>>>(
        o_bf, WoT, out, x, ROWS, DIM, DIM);

    // 7. m = rms_norm(d_out) -> m_bf
    rmsnorm_bf16_kernel<<<ROWS, 256, 0, stream>>>(out, m_bf);

    // 8. fc = relu(m @ W_fc)^2 -> bf16 (256^2 8-phase)
    gemm256<3, unsigned short><<<dim3(DFF_ / 256, ROWS / 256), 512, 0, stream>>>(
        m_bf, WfcT, fc_bf, nullptr, ROWS, DFF_, DIM);

    // 9. d_out += fc @ W_proj (128x256 8-phase, K=4096, 256 blocks)
    gemm128n<2><<<dim3(1024 / 256, ROWS / 128), 512, 0, stream>>>(
        fc_bf, WprT, out, out, ROWS, DIM, DFF_);
}